// Round 6
// baseline (263.152 us; speedup 1.0000x reference)
//
#include <hip/hip_runtime.h>

#define B_   64
#define NQ_  1024
#define L_   128
#define E_   8192
#define M_   (B_*NQ_)
#define LDP  136        // padded LDS row stride (shorts)
#define TILE 2176       // 16*LDP u16 per tile

typedef unsigned short u16;
typedef unsigned int   u32;
typedef unsigned long long u64;
typedef __attribute__((ext_vector_type(8))) short short8;
typedef __attribute__((ext_vector_type(4))) float floatx4;

#define WVB() __builtin_amdgcn_wave_barrier()

__device__ __forceinline__ int imax2(int a, int b) { return a > b ? a : b; }
__device__ __forceinline__ int imin2(int a, int b) { return a < b ? a : b; }

__device__ __forceinline__ u16 f2bf(float f) {
    union { float f; u32 u; } v; v.f = f;
    return (u16)((v.u + 0x7fffu + ((v.u >> 16) & 1u)) >> 16);
}
__device__ __forceinline__ float bf2f(u16 u) {
    union { u32 u; float f; } v; v.u = ((u32)u) << 16;
    return v.f;
}
__device__ __forceinline__ float bf2f_lo(u32 jv) { return __uint_as_float(jv << 16); }
__device__ __forceinline__ float bf2f_hi(u32 jv) { return __uint_as_float(jv & 0xffff0000u); }
__device__ __forceinline__ floatx4 mfma16(short8 a, short8 b, floatx4 c) {
    return __builtin_amdgcn_mfma_f32_16x16x32_bf16(a, b, c, 0, 0, 0);
}
__device__ __forceinline__ short8 sfrag(const u16* t, int r0, int kb, int lane) {
    return *(const short8*)(t + (r0 + (lane & 15)) * LDP + kb * 32 + (lane >> 4) * 8);
}
// fragment-major weight fetch: coalesced 16B/lane from global (L2-hot)
__device__ __forceinline__ short8 wfrag(const u16* wf, int nt, int kb, int lane) {
    return *(const short8*)(wf + (((kb << 3) + nt) * 64 + lane) * 8);
}
__device__ __forceinline__ void frag_flush(const u16* t, u16* wf, int nt, int lane) {
#pragma unroll
    for (int kb = 0; kb < 4; ++kb)
        *(short8*)(wf + (((kb << 3) + nt) * 64 + lane) * 8) = sfrag(t, 0, kb, lane);
}
__device__ __forceinline__ short8 frag_cvt(const float* base, int r0, int ld, int kb, int lane) {
    const float* p = base + (size_t)(r0 + (lane & 15)) * ld + kb * 32 + (lane >> 4) * 8;
    short8 s;
#pragma unroll
    for (int j = 0; j < 8; ++j) s[j] = (short)f2bf(p[j]);
    return s;
}
__device__ __forceinline__ void tile_store(u16* t, const floatx4* acc, int lane) {
    int col = lane & 15, qd = lane >> 4;
#pragma unroll
    for (int nt = 0; nt < 8; ++nt)
#pragma unroll
        for (int r = 0; r < 4; ++r)
            t[(qd * 4 + r) * LDP + nt * 16 + col] = f2bf(acc[nt][r]);
}
__device__ __forceinline__ void tile_flush(const u16* t, u16* g, int lane) {
#pragma unroll
    for (int it = 0; it < 4; ++it) {
        int chunk = it * 64 + lane, row = chunk >> 4, c8 = chunk & 15;
        *(uint4*)(g + (size_t)row * 128 + c8 * 8) = *(const uint4*)(t + row * LDP + c8 * 8);
    }
}
// XCD-bijective swizzle for 1024 blocks (node0): batch b only on XCD b&7.
__device__ __forceinline__ int blk_swz() {
    int r = blockIdx.x;
    int b = (((r >> 3) & 7) << 3) | (r & 7);
    return b * 16 + (r >> 6);
}

struct P {
    const int* ei; const float* attr; const float* z0;
    const float* e_w1; const float* e_b1; const float* e_w2; const float* e_b2;
    const float* n_w1; const float* n_b1; const float* ln_g; const float* ln_b;
    const float* n_w2; const float* n_b2;
    int* ofs; int2* ta; int* perm; float* degf;
    u16* wf;        // 6 fragment-major slots: 0=Wc0 1=Wd 2=We 3=Wf 4=Wc1 5=n2_1
    u16* w_n20;     // n2_0 row-major (fin GEMV)
    float* wl; float* vb2;
    float* rx; float* rci; float* rcj; float* rh; float* mx0;
    u16* c0t; u16* t1g; u16* ci1; u16* cj1;   // t1g fragment-major
    float* out;
};

// ---------------------------------------------------------------------------
// Setup, 20 blocks:
// 0 CSR + degree counting-sort perm; 1-2 n2_0 cvt; 3 n2_1->frag;
// 4-13 product GEMMs (B staged via LDS-transpose, coalesced);
// 14 rx; 15-17 rci/rcj/rh; 18 c0; 19 vb2+wl+zero mx0
// ---------------------------------------------------------------------------
__global__ __launch_bounds__(256) void k_setup(P p) {
    __shared__ __align__(16) char smem[35072];
    int tid = threadIdx.x, blk = blockIdx.x;
    int lane = tid & 63, w = tid >> 6, col = lane & 15, qd = lane >> 4;

    if (blk == 0) {                               // CSR build + degree sort
        int* cnt  = (int*)smem;                   // 1024
        int* wsum = cnt + 1024;                   // 4
        int* dh   = wsum + 4;                     // 64
        int* db   = dh + 64;                      // 64
        int* flag = db + 64;                      // 1
#pragma unroll
        for (int i = 0; i < 4; ++i) cnt[tid + i * 256] = 0;
        if (tid < 64) dh[tid] = 0;
        if (tid == 0) *flag = 1;
        __syncthreads();
        if (tid < 100 && p.ei[2 * tid + 1] != 0) atomicAnd(flag, 0);
        __syncthreads();
        int i64 = *flag;
        for (int e = tid; e < E_; e += 256) {
            int s = i64 ? p.ei[2 * e] : p.ei[e];
            atomicAdd(&cnt[s], 1);
        }
        __syncthreads();
        int q0 = tid * 4;
        int c0 = cnt[q0], c1 = cnt[q0 + 1], c2 = cnt[q0 + 2], c3 = cnt[q0 + 3];
        int tsum = c0 + c1 + c2 + c3, incl = tsum;
#pragma unroll
        for (int o = 1; o < 64; o <<= 1) {
            int t = __shfl_up(incl, o, 64);
            if (lane >= o) incl += t;
        }
        if (lane == 63) wsum[w] = incl;
        atomicAdd(&dh[imin2(c0, 63)], 1); atomicAdd(&dh[imin2(c1, 63)], 1);
        atomicAdd(&dh[imin2(c2, 63)], 1); atomicAdd(&dh[imin2(c3, 63)], 1);
        __syncthreads();
        int wo = 0;
        for (int i = 0; i < w; ++i) wo += wsum[i];
        int base = wo + incl - tsum;
        p.ofs[q0] = base; p.ofs[q0 + 1] = base + c0;
        p.ofs[q0 + 2] = base + c0 + c1; p.ofs[q0 + 3] = base + c0 + c1 + c2;
        p.degf[q0] = (float)c0; p.degf[q0 + 1] = (float)c1;
        p.degf[q0 + 2] = (float)c2; p.degf[q0 + 3] = (float)c3;
        if (tid == 0) p.ofs[NQ_] = E_;
        __syncthreads();
        cnt[q0] = base; cnt[q0 + 1] = base + c0;
        cnt[q0 + 2] = base + c0 + c1; cnt[q0 + 3] = base + c0 + c1 + c2;
        if (tid < 64) {                           // exclusive scan of 64 bins
            int v = dh[tid], inc = v;
#pragma unroll
            for (int o = 1; o < 64; o <<= 1) {
                int t = __shfl_up(inc, o, 64);
                if (tid >= o) inc += t;
            }
            db[tid] = inc - v;
        }
        __syncthreads();
        for (int e = tid; e < E_; e += 256) {
            int s = i64 ? p.ei[2 * e]        : p.ei[e];
            int t = i64 ? p.ei[2 * (E_ + e)] : p.ei[E_ + e];
            int pos = atomicAdd(&cnt[s], 1);
            p.ta[pos] = make_int2(t << 6, __float_as_int(p.attr[e]));
        }
        p.perm[atomicAdd(&db[imin2(c0, 63)], 1)] = q0;
        p.perm[atomicAdd(&db[imin2(c1, 63)], 1)] = q0 + 1;
        p.perm[atomicAdd(&db[imin2(c2, 63)], 1)] = q0 + 2;
        p.perm[atomicAdd(&db[imin2(c3, 63)], 1)] = q0 + 3;
        if (tid == 0) p.ta[E_] = make_int2(0, 0);   // pad slot
    } else if (blk <= 2) {                        // n2_0 row-major cvt, 2 halves
        int base = (blk - 1) * 8192;
        for (int idx = tid; idx < 8192; idx += 256)
            p.w_n20[base + idx] = f2bf(p.n_w2[base + idx]);
    } else if (blk == 3) {                        // n2_1 -> fragment-major slot 5
        const float* src = p.n_w2 + 16384;
        u16* dst = p.wf + 5 * 16384;
        for (int pr = w; pr < 32; pr += 4) {      // pr = kb*8+nt
            int kb = pr >> 3, nt = pr & 7;
            const float* s = src + (nt * 16 + col) * 128 + kb * 32 + qd * 8;
            short8 v;
#pragma unroll
            for (int j = 0; j < 8; ++j) v[j] = (short)f2bf(s[j]);
            *(short8*)(dst + (pr * 64 + lane) * 8) = v;
        }
    } else if (blk <= 13) {                       // product GEMMs, LDS-staged B
        int g = (blk - 4) >> 1, part = (blk - 4) & 1;
        const float* Pm; const float* Q; int ldp; u16* D;
        switch (g) {
            case 0:  Pm = p.n_w1 + 128;             ldp = 256; Q = p.e_w2;         D = p.wf;             break;
            case 1:  Pm = p.n_w1 + 32768 + 128;     ldp = 256; Q = p.e_w2 + 16384; D = p.wf + 4 * 16384; break;
            case 2:  Pm = p.e_w1 + 128 * 257;       ldp = 257; Q = p.n_w2;         D = p.wf + 1 * 16384; break;
            case 3:  Pm = p.e_w1 + 128 * 257 + 128; ldp = 257; Q = p.n_w2;         D = p.wf + 2 * 16384; break;
            default: Pm = p.n_w1 + 32768;           ldp = 256; Q = p.n_w2;         D = p.wf + 3 * 16384; break;
        }
        float* QT  = (float*)smem;                // [128][33] transposed panel
        u16* slots = (u16*)(smem + 16896);        // 4 x TILE
        int tile = part * 4 + w;                  // 0..7, one 16-row tile per wave
        int r0 = tile * 16;
        floatx4 acc[8] = {};
        for (int kb = 0; kb < 4; ++kb) {
            __syncthreads();
            // coalesced load of Q[kb*32..+32][0..128] -> QT[col][row]
#pragma unroll
            for (int i = 0; i < 4; ++i) {
                int off = (tid + i * 256) * 4;
                int r = off >> 7, c = off & 127;
                float4 v = *(const float4*)(Q + (size_t)(kb * 32 + r) * 128 + c);
                QT[(c + 0) * 33 + r] = v.x; QT[(c + 1) * 33 + r] = v.y;
                QT[(c + 2) * 33 + r] = v.z; QT[(c + 3) * 33 + r] = v.w;
            }
            __syncthreads();
            short8 a = frag_cvt(Pm, r0, ldp, kb, lane);
#pragma unroll
            for (int nt = 0; nt < 8; ++nt) {
                short8 bq;                        // B[k][n] = Q[k][n] from LDS
#pragma unroll
                for (int j = 0; j < 8; ++j)
                    bq[j] = (short)f2bf(QT[(nt * 16 + col) * 33 + qd * 8 + j]);
                acc[nt] = mfma16(a, bq, acc[nt]);
            }
        }
        __syncthreads();
        u16* slot = slots + w * TILE;
        tile_store(slot, acc, lane); WVB();
        frag_flush(slot, D, tile, lane);
    } else if (blk == 14) {                       // rx = z0@n1a0^T + n_b1_0
        int r0 = w * 16;
        floatx4 acc[8] = {};
#pragma unroll
        for (int kb = 0; kb < 4; ++kb) {
            short8 a = frag_cvt(p.z0, r0, 128, kb, lane);
#pragma unroll
            for (int nt = 0; nt < 8; ++nt)
                acc[nt] = mfma16(a, frag_cvt(p.n_w1, nt * 16, 256, kb, lane), acc[nt]);
        }
#pragma unroll
        for (int nt = 0; nt < 8; ++nt) {
            int cg = nt * 16 + col; float bv = p.n_b1[cg];
#pragma unroll
            for (int r = 0; r < 4; ++r) p.rx[(r0 + qd * 4 + r) * 128 + cg] = acc[nt][r] + bv;
        }
    } else if (blk <= 17) {                       // rci/rcj/rh = (z0+n_b2_0)@W^T (+bias)
        int r0 = w * 16;
        const float* Wp; int ld; const float* bias; float* dst;
        if (blk == 15)      { Wp = p.e_w1 + 128 * 257;       ld = 257; bias = p.e_b1 + 128; dst = p.rci; }
        else if (blk == 16) { Wp = p.e_w1 + 128 * 257 + 128; ld = 257; bias = nullptr;      dst = p.rcj; }
        else                { Wp = p.n_w1 + 32768;           ld = 256; bias = p.n_b1 + 128; dst = p.rh;  }
        floatx4 acc[8] = {};
#pragma unroll
        for (int kb = 0; kb < 4; ++kb) {
            short8 a;
            int rr = (r0 + col) * 128, kk = kb * 32 + qd * 8;
#pragma unroll
            for (int j = 0; j < 8; ++j) a[j] = (short)f2bf(p.z0[rr + kk + j] + p.n_b2[kk + j]);
#pragma unroll
            for (int nt = 0; nt < 8; ++nt)
                acc[nt] = mfma16(a, frag_cvt(Wp, nt * 16, ld, kb, lane), acc[nt]);
        }
#pragma unroll
        for (int nt = 0; nt < 8; ++nt) {
            int cg = nt * 16 + col;
            float bv = bias ? bias[cg] : 0.0f;
#pragma unroll
            for (int r = 0; r < 4; ++r) dst[(r0 + qd * 4 + r) * 128 + cg] = acc[nt][r] + bv;
        }
    } else if (blk == 18) {                       // c0 = z0@(W1a0+W1b0)^T + e_b1_0
        int r0 = w * 16;
        floatx4 a1[8] = {};
#pragma unroll
        for (int kb = 0; kb < 4; ++kb) {
            short8 a = frag_cvt(p.z0, r0, 128, kb, lane);
#pragma unroll
            for (int nt = 0; nt < 8; ++nt) {
                a1[nt] = mfma16(a, frag_cvt(p.e_w1,       nt * 16, 257, kb, lane), a1[nt]);
                a1[nt] = mfma16(a, frag_cvt(p.e_w1 + 128, nt * 16, 257, kb, lane), a1[nt]);
            }
        }
#pragma unroll
        for (int nt = 0; nt < 8; ++nt) {
            float bv = p.e_b1[nt * 16 + col];
#pragma unroll
            for (int r = 0; r < 4; ++r) a1[nt][r] += bv;
        }
        u16* slot = (u16*)smem + w * TILE;
        tile_store(slot, a1, lane); WVB();
        tile_flush(slot, p.c0t + (size_t)r0 * 128, lane);
    } else {                                      // vb2 (vectorized) + wl + zero mx0
        int k = tid >> 7, c = tid & 127;
        const float4* wp = (const float4*)(p.n_w1 + k * 32768 + c * 256 + 128);
        const float4* bp = (const float4*)(p.e_b2 + k * 128);
        float s0 = 0.f, s1 = 0.f, s2 = 0.f, s3 = 0.f;
#pragma unroll
        for (int n4 = 0; n4 < 32; ++n4) {
            float4 a = wp[n4], bv = bp[n4];
            s0 += a.x * bv.x; s1 += a.y * bv.y; s2 += a.z * bv.z; s3 += a.w * bv.w;
        }
        p.vb2[tid] = (s0 + s1) + (s2 + s3);
        p.wl[tid]  = p.e_w1[k * 128 * 257 + c * 257 + 256];
        for (int i = tid; i < 8192; i += 256) p.mx0[i] = 0.0f;
    }
}

// ---------------------------------------------------------------------------
// node0, 1024 blocks x 4 waves x 16 rows (sorted rows, lean/tail edge phase):
// fused round-0 edge (no gather) -> x0 GEMM -> LN -> mx0 atomics;
// ci1 physical rows; cj1 scattered to ORIGINAL q; t1 fragment-major.
// ---------------------------------------------------------------------------
__global__ __launch_bounds__(256, 4) void k_node0(P p) {
    __shared__ __align__(16) char smem[35072];
    u16* xt = (u16*)smem;                  // 4 waves x 1 tile
    u16* ob = (u16*)(smem + 17408);        // 4 waves x 1 tile staging
    int* qmap = (int*)(smem + 34816);      // 4 waves x 16 ints
    int tid = threadIdx.x, lane = tid & 63, w = tid >> 6;
    int col = lane & 15, qd = lane >> 4;
    int blk = blk_swz();
    int rowbase = blk * 64 + w * 16;
    int b = blk >> 4;
    {   // qmap: wave W handles sorted groups (W, 127-W)
        int W = (blk & 15) * 4 + w;
        if (lane < 16)
            qmap[w * 16 + lane] = p.perm[lane < 8 ? W * 8 + lane : (127 - W) * 8 + lane - 8];
        WVB();
    }

    // ---- fused round-0 edge aggregation (sorted, lean/tail, 8-row groups) ----
    {
        u32 cv = ((const u32*)p.c0t)[b * 64 + lane];
        float cx = bf2f((u16)(cv & 0xffffu)), cy = bf2f((u16)(cv >> 16));
        float2 wl2 = ((const float2*)p.wl)[lane];
        const int* tay = (const int*)p.ta;        // .y at 2*idx+1
        for (int g2 = 0; g2 < 2; ++g2) {
            int st[8], en[8];
            float ax[8] = {}, ay[8] = {};
#pragma unroll
            for (int j = 0; j < 8; ++j) {
                int q = qmap[w * 16 + g2 * 8 + j];
                st[j] = p.ofs[q]; en[j] = p.ofs[q + 1];
            }
            int mn = en[0] - st[0], mx = mn;
#pragma unroll
            for (int j = 1; j < 8; ++j) {
                mn = imin2(mn, en[j] - st[j]); mx = imax2(mx, en[j] - st[j]);
            }
            float ac[8];
#pragma unroll
            for (int j = 0; j < 8; ++j) {         // clamped init prefetch
                int last = en[j] - 1;
                int safe = st[j] < en[j] ? st[j] : (last >= 0 ? last : 0);
                ac[j] = __int_as_float(tay[2 * safe + 1]);
            }
            for (int k2 = 0; k2 < mn; ++k2) {     // lean: no masks, no clamps
                float an[8];
#pragma unroll
                for (int j = 0; j < 8; ++j) an[j] = __int_as_float(tay[2 * (st[j] + k2 + 1) + 1]);
#pragma unroll
                for (int j = 0; j < 8; ++j) {
                    ax[j] += fmaxf(cx + ac[j] * wl2.x, 0.f);
                    ay[j] += fmaxf(cy + ac[j] * wl2.y, 0.f);
                    ac[j] = an[j];
                }
            }
            for (int k2 = mn; k2 < mx; ++k2) {    // masked tail
                float an[8];
#pragma unroll
                for (int j = 0; j < 8; ++j) {
                    int idx = st[j] + k2 + 1, last = en[j] - 1;
                    int safe = idx < en[j] ? idx : (last >= 0 ? last : 0);
                    an[j] = __int_as_float(tay[2 * safe + 1]);
                }
#pragma unroll
                for (int j = 0; j < 8; ++j) {
                    bool v = st[j] + k2 < en[j];
                    ax[j] += v ? fmaxf(cx + ac[j] * wl2.x, 0.f) : 0.f;
                    ay[j] += v ? fmaxf(cy + ac[j] * wl2.y, 0.f) : 0.f;
                    ac[j] = an[j];
                }
            }
#pragma unroll
            for (int j = 0; j < 8; ++j) {
                int r = g2 * 8 + j;
                u32* tp = (u32*)(xt + (size_t)w * TILE + r * LDP);
                tp[lane] = (u32)f2bf(ax[j]) | ((u32)f2bf(ay[j]) << 16);
            }
        }
    }
    WVB();

    floatx4 xa[8] = {};
#pragma unroll
    for (int kb = 0; kb < 4; ++kb) {
        short8 a = sfrag(xt + w * TILE, 0, kb, lane);
#pragma unroll
        for (int nt = 0; nt < 8; ++nt) xa[nt] = mfma16(a, wfrag(p.wf, nt, kb, lane), xa[nt]);
    }
    WVB();
    float s8[8] = {};
#pragma unroll
    for (int nt = 0; nt < 8; ++nt) {
        int cg = nt * 16 + col;
        float base = p.rx[b * 128 + cg], vb = p.vb2[cg];
#pragma unroll
        for (int r = 0; r < 4; ++r) {
            int q = qmap[w * 16 + qd * 4 + r];
            xa[nt][r] = fmaxf(xa[nt][r] + base + p.degf[q] * vb, 0.f);
        }
    }
#pragma unroll
    for (int r = 0; r < 4; ++r) {
        float s = 0.f, s2 = 0.f;
#pragma unroll
        for (int nt = 0; nt < 8; ++nt) { float v = xa[nt][r]; s += v; s2 += v * v; }
#pragma unroll
        for (int o = 1; o < 16; o <<= 1) { s += __shfl_xor(s, o, 64); s2 += __shfl_xor(s2, o, 64); }
        float mu = s * (1.f / 128.f), var = s2 * (1.f / 128.f) - mu * mu;
        float rs = rsqrtf(var + 1e-5f);
#pragma unroll
        for (int nt = 0; nt < 8; ++nt) {
            int cg = nt * 16 + col;
            float xv = (xa[nt][r] - mu) * rs * p.ln_g[cg] + p.ln_b[cg];
            xa[nt][r] = xv;
            s8[nt] += xv;
        }
    }
    tile_store(xt + w * TILE, xa, lane);
#pragma unroll
    for (int nt = 0; nt < 8; ++nt) {
        s8[nt] += __shfl_xor(s8[nt], 16, 64);
        s8[nt] += __shfl_xor(s8[nt], 32, 64);
    }
    if (lane < 16) {
#pragma unroll
        for (int nt = 0; nt < 8; ++nt)
            atomicAdd(p.mx0 + b * 128 + nt * 16 + lane, s8[nt]);
    }
    WVB();
#pragma unroll
    for (int ph = 0; ph < 3; ++ph) {
        const u16* wfp = p.wf + ((ph == 0) ? 1 : (ph == 1) ? 2 : 3) * 16384;
        const float* rt = (ph == 0) ? p.rci : (ph == 1) ? p.rcj : p.rh;
        floatx4 ca[8] = {};
#pragma unroll
        for (int kb = 0; kb < 4; ++kb) {
            short8 a = sfrag(xt + w * TILE, 0, kb, lane);
#pragma unroll
            for (int nt = 0; nt < 8; ++nt) ca[nt] = mfma16(a, wfrag(wfp, nt, kb, lane), ca[nt]);
        }
#pragma unroll
        for (int nt = 0; nt < 8; ++nt) {
            float rc = rt[b * 128 + nt * 16 + col];
#pragma unroll
            for (int r = 0; r < 4; ++r) ca[nt][r] += rc;
        }
        if (ph == 2) {                            // t1 -> fragment-major, 8B/lane
            u64* t1f = (u64*)p.t1g;
            int tile = blk * 4 + w;               // physical tile index
#pragma unroll
            for (int nt = 0; nt < 8; ++nt) {
                u32 lo = (u32)f2bf(ca[nt][0]) | ((u32)f2bf(ca[nt][1]) << 16);
                u32 hi = (u32)f2bf(ca[nt][2]) | ((u32)f2bf(ca[nt][3]) << 16);
                t1f[(size_t)(tile * 8 + nt) * 64 + lane] = (u64)lo | ((u64)hi << 32);
            }
        } else if (ph == 0) {                     // ci1: physical rows, contiguous
            tile_store(ob + w * TILE, ca, lane);
            WVB();
            tile_flush(ob + w * TILE, p.ci1 + (size_t)rowbase * 128, lane);
            WVB();
        } else {                                  // cj1: scatter to ORIGINAL q
            tile_store(ob + w * TILE, ca, lane);
            WVB();
#pragma unroll
            for (int it = 0; it < 4; ++it) {
                int chunk = it * 64 + lane, row = chunk >> 4, c8 = chunk & 15;
                int q = qmap[w * 16 + row];
                *(uint4*)(p.cj1 + ((size_t)b * NQ_ + q) * 128 + c8 * 8) =
                    *(const uint4*)(ob + w * TILE + row * LDP + c8 * 8);
            }
            WVB();
        }
    }
}

// ---------------------------------------------------------------------------
// node1, 4096 blocks x 128 thr (2 waves, ONE 16-row tile per block):
// each wave gathers 8 balanced rows (4 small-deg + 4 big-deg, lean 8-stream
// then lean 4-stream then masked tails); both waves redundantly compute the
// x1 GEMM + LN (MFMA is ~free); wave0 does n21 reduce + atomics; fin GEMV.
// 8192 gather-waves -> 32 waves/CU (2x round-4 latency hiding).
// ---------------------------------------------------------------------------
__global__ __launch_bounds__(128, 8) void k_node1(P p) {
    __shared__ __align__(16) char smem[4480];
    u16* xt = (u16*)smem;                    // 1 tile
    int* qmap = (int*)(smem + 4352);         // 16 ints
    int tid = threadIdx.x, lane = tid & 63, w = tid >> 6;  // w in {0,1}
    int col = lane & 15, qd = lane >> 4;
    int r4 = blockIdx.x;
    int b  = (((r4 >> 3) & 7) << 3) | (r4 & 7);   // XCD-bijective: b on XCD b&7
    int nb = b * 64 + (r4 >> 6);                  // physical tile id
    int W  = nb & 63;                              // sorted-pair index
    if (tid < 16) qmap[tid] = p.perm[tid < 8 ? W * 8 + tid : (127 - W) * 8 + tid - 8];
    __syncthreads();

    // ---- fused round-1 gather: wave w rows {w*4+0..3, w*4+8..11(+8)} ----
    {
        float2 wl2 = ((const float2*)(p.wl + 128))[lane];
        const u32* cip = (const u32*)p.ci1;
        const u32* cjp = (const u32*)p.cj1 + (size_t)b * NQ_ * 64;
        int rr[8], st[8], en[8];
        float ax[8] = {}, ay[8] = {}, cx[8], cy[8];
#pragma unroll
        for (int j = 0; j < 8; ++j) {
            rr[j] = w * 4 + (j & 3) + 8 * (j >> 2);   // j 0-3: small group, 4-7: big
            int prow = nb * 16 + rr[j];
            u32 cv = cip[(size_t)prow * 64 + lane];
            cx[j] = bf2f((u16)(cv & 0xffffu)); cy[j] = bf2f((u16)(cv >> 16));
            int q = qmap[rr[j]];
            st[j] = p.ofs[q]; en[j] = p.ofs[q + 1];
        }
        int mA = en[0] - st[0], MA = mA, mB = en[4] - st[4], MB = mB;
#pragma unroll
        for (int j = 1; j < 4; ++j) {
            mA = imin2(mA, en[j] - st[j]); MA = imax2(MA, en[j] - st[j]);
        }
#pragma unroll
        for (int j = 5; j < 8; ++j) {
            mB = imin2(mB, en[j] - st[j]); MB = imax2(MB, en[j] - st[j]);
        }
        int m8 = imin2(mA, mB);
        int tc[8]; float ac[8];
#pragma unroll
        for (int j = 0; j < 8; ++j) {             // clamped init prefetch
            int last = en[j] - 1;
            int safe = st[j] < en[j] ? st[j] : (last >= 0 ? last : 0);
            int2 tv = p.ta[safe];
            tc[j] = tv.x; ac[j] = __int_as_float(tv.y);
        }
        for (int k2 = 0; k2 < m8; ++k2) {         // seg1: 8-stream lean
            u32 jv[8];
#pragma unroll
            for (int j = 0; j < 8; ++j) jv[j] = cjp[(u32)(tc[j] + lane)];
            int2 tv[8];
#pragma unroll
            for (int j = 0; j < 8; ++j) tv[j] = p.ta[st[j] + k2 + 1];
#pragma unroll
            for (int j = 0; j < 8; ++j) {
                ax[j] += fmaxf(cx[j] + bf2f_lo(jv[j]) + ac[j] * wl2.x, 0.f);
                ay[j] += fmaxf(cy[j] + bf2f_hi(jv[j]) + ac[j] * wl2.y, 0.f);
                tc[j] = tv[j].x; ac[j] = __int_as_float(tv[j].y);
            }
        }
        for (int k2 = m8; k2 < MA; ++k2) {        // A tail: masked, j 0-3
            u32 jv[4];
#pragma unroll
            for (int j = 0; j < 4; ++j) jv[j] = cjp[(u32)(tc[j] + lane)];
            int2 tv[4];
#pragma unroll
            for (int j = 0; j < 4; ++j) {
                int idx = st[j] + k2 + 1, last = en[j] - 1;
                int safe = idx < en[j] ? idx : (last >= 0 ? last : 0);
                tv[j] = p.ta[safe];
            }
#pragma unroll
            for (int j = 0; j < 4; ++j) {
                bool v = st[j] + k2 < en[j];
                float vx = fmaxf(cx[j] + bf2f_lo(jv[j]) + ac[j] * wl2.x, 0.f);
                float vy = fmaxf(cy[j] + bf2f_hi(jv[j]) + ac[j] * wl2.y, 0.f);
                ax[j] += v ? vx : 0.f;
                ay[j] += v ? vy : 0.f;
                tc[j] = tv[j].x; ac[j] = __int_as_float(tv[j].y);
            }
        }
        for (int k2 = m8; k2 < mB; ++k2) {        // B continue: lean, j 4-7
            u32 jv[4];
#pragma unroll
            for (int j = 4; j < 8; ++j) jv[j - 4] = cjp[(u32)(tc[j] + lane)];
            int2 tv[4];
#pragma unroll
            for (int j = 4; j < 8; ++j) tv[j - 4] = p.ta[st[j] + k2 + 1];
#pragma unroll
            for (int j = 4; j < 8; ++j) {
                ax[j] += fmaxf(cx[j] + bf2f_lo(jv[j - 4]) + ac[j] * wl2.x, 0.f);
                ay[j] += fmaxf(cy[j] + bf2f_hi(jv[j - 4]) + ac[j] * wl2.y, 0.f);
                tc[j] = tv[j - 4].x; ac[j] = __int_as_float(tv[j - 4].y);
            }
        }
        for (int k2 = imax2(m8, mB); k2 < MB; ++k2) {   // B tail: masked
            u32 jv[4];
#pragma unroll
            for (int j = 4; j < 8; ++j) jv[j - 4] = cjp[(u32)(tc[j] + lane)];
            int2 tv[4];
#pragma unroll
            for (int j = 4; j < 8; ++j) {
                int idx = st[j] + k2 + 1, last = en[j] - 1;
                int safe = idx < en[j] ? idx : (last >= 0 ? last : 0);
                tv[j - 4] = p.ta[safe];
            }
#pragma unroll
            for (int j = 4; j < 8; ++j) {
                bool v = st[j] + k2 < en[j];
                float vx = fmaxf(cx[j] + bf2f_lo(jv[j - 4]) + ac[j] * wl2.x, 0.f);
                float vy = fmaxf(cy[j] + bf2f_hi(jv[j - 4]) + ac[j] * wl2.y, 0.f);
                ax[j] += v ? vx : 0.f;
                ay[j] += v ? vy : 0.f;
                tc[j] = tv[j - 4].x; ac[j] = __int_as_float(tv[j - 4].y);
            }
        }
#pragma unroll
        for (int j = 0; j < 8; ++j) {
            u32* tp = (u32*)(xt + rr[j] * LDP);
            tp[lane] = (u32)f2bf(ax[j]) | ((u32)f2bf(ay[j]) << 16);
        }
    }
    __syncthreads();

    // ---- x1 GEMM (both waves, redundant — keeps LN wave-local) ----
    const u16* wc1 = p.wf + 4 * 16384;
    floatx4 x1[8] = {};
#pragma unroll
    for (int kb = 0; kb < 4; ++kb) {
        short8 a = sfrag(xt, 0, kb, lane);
#pragma unroll
        for (int nt = 0; nt < 8; ++nt) x1[nt] = mfma16(a, wfrag(wc1, nt, kb, lane), x1[nt]);
    }
    const float* vb21 = p.vb2 + 128;
    const u64* t1f = (const u64*)p.t1g;
#pragma unroll
    for (int nt = 0; nt < 8; ++nt) {
        int cg = nt * 16 + col;
        float vb = vb21[cg];
        u64 tv = t1f[(size_t)(nb * 8 + nt) * 64 + lane];   // coalesced 8B/lane
        float tvf[4] = { bf2f((u16)tv),         bf2f((u16)(tv >> 16)),
                         bf2f((u16)(tv >> 32)), bf2f((u16)(tv >> 48)) };
#pragma unroll
        for (int r = 0; r < 4; ++r) {
            int q = qmap[qd * 4 + r];
            x1[nt][r] = fmaxf(x1[nt][r] + tvf[r] + p.degf[q] * vb, 0.f);
        }
    }
#pragma unroll
    for (int r = 0; r < 4; ++r) {
        float s = 0.f, s2 = 0.f;
#pragma unroll
        for (int nt = 0; nt < 8; ++nt) { float v = x1[nt][r]; s += v; s2 += v * v; }
#pragma unroll
        for (int o = 1; o < 16; o <<= 1) { s += __shfl_xor(s, o, 64); s2 += __shfl_xor(s2, o, 64); }
        float mu = s * (1.f / 128.f), var = s2 * (1.f / 128.f) - mu * mu;
        float rs = rsqrtf(var + 1e-5f);
#pragma unroll
        for (int nt = 0; nt < 8; ++nt) {
            int cg = nt * 16 + col;
            x1[nt][r] = (x1[nt][r] - mu) * rs * p.ln_g[128 + cg] + p.ln_b[128 + cg];
        }
    }
    __syncthreads();                             // both waves done reading xt(S)
    if (w == 0) {                                // wave0: n21 reduce via xt
        tile_store(xt, x1, lane);
        WVB();
        const u16* n21 = p.wf + 5 * 16384;
        float s9[8] = {};
        floatx4 ma[8] = {};
#pragma unroll
        for (int kb = 0; kb < 4; ++kb) {
            short8 a = sfrag(xt, 0, kb, lane);
#pragma unroll
            for (int nt = 0; nt < 8; ++nt) ma[nt] = mfma16(a, wfrag(n21, nt, kb, lane), ma[nt]);
        }
#pragma unroll
        for (int nt = 0; nt < 8; ++nt) {
#pragma unroll
            for (int r = 0; r < 4; ++r) s9[nt] += ma[nt][r];
            s9[nt] += __shfl_xor(s9[nt], 16, 64);
            s9[nt] += __shfl_xor(s9[nt], 32, 64);
        }
        if (lane < 16) {
#pragma unroll
            for (int nt = 0; nt < 8; ++nt)
                atomicAdd(p.out + b * 128 + nt * 16 + lane, s9[nt] * (1.f / 1024.f));
        }
    }
    // fin: out[b] += z0[b] + n_b2_0 + n_b2_1 + mx0[b]@n2_0^T / 1024
    if ((nb & 63) == 0) {
        int c = tid;
        const float* mx = p.mx0 + b * 128;
        float s = 0.f;
#pragma unroll
        for (int k8 = 0; k8 < 16; ++k8) {
            short8 wv = *(const short8*)(p.w_n20 + c * 128 + k8 * 8);
            const float* mxp = mx + k8 * 8;
#pragma unroll
            for (int j = 0; j < 8; ++j) s += mxp[j] * bf2f((u16)wv[j]);
        }
        float acc = p.z0[b * 128 + c] + p.n_b2[c] + p.n_b2[128 + c] + s * (1.f / 1024.f);
        atomicAdd(p.out + b * 128 + c, acc);
    }
}

// ---------------------------------------------------------------------------
extern "C" void kernel_launch(void* const* d_in, const int* in_sizes, int n_in,
                              void* d_out, int out_size, void* d_ws, size_t ws_size,
                              hipStream_t stream) {
    P p;
    p.z0   = (const float*)d_in[0];
    p.ei   = (const int*)d_in[1];
    p.attr = (const float*)d_in[2];
    p.e_w1 = (const float*)d_in[4];
    p.e_b1 = (const float*)d_in[5];
    p.e_w2 = (const float*)d_in[6];
    p.e_b2 = (const float*)d_in[7];
    p.n_w1 = (const float*)d_in[8];
    p.n_b1 = (const float*)d_in[9];
    p.ln_g = (const float*)d_in[10];
    p.ln_b = (const float*)d_in[11];
    p.n_w2 = (const float*)d_in[12];
    p.n_b2 = (const float*)d_in[13];
    p.out  = (float*)d_out;

    const size_t H = (size_t)M_ * L_;
    float* f  = (float*)d_ws;
    p.degf = f;                           // 1024
    p.wl   = f + 1024;                    // 256
    p.vb2  = p.wl + 256;                  // 256
    p.rx   = p.vb2 + 256;                 // 8192
    p.rci  = p.rx + 8192;                 // 8192
    p.rcj  = p.rci + 8192;                // 8192
    p.rh   = p.rcj + 8192;                // 8192
    p.mx0  = p.rh + 8192;                 // 8192
    p.ofs  = (int*)(p.mx0 + 8192);        // 1056
    p.perm = p.ofs + 1056;                // 1024
    p.ta   = (int2*)(p.perm + 1024);      // E_+8 int2
    p.wf    = (u16*)(p.ta + E_ + 8);      // 6*16384
    p.w_n20 = p.wf + 6 * 16384;           // 16384
    p.c0t   = p.w_n20 + 16384;            // 8192
    p.t1g   = p.c0t + 8192;               // H (fragment-major)
    p.ci1   = p.t1g + H;                  // H
    p.cj1   = p.ci1 + H;                  // H

    hipMemsetAsync(p.out, 0, 8192 * sizeof(float), stream);

    k_setup<<<20, 256, 0, stream>>>(p);
    k_node0<<<1024, 256, 0, stream>>>(p);
    k_node1<<<4096, 128, 0, stream>>>(p);
}

// Round 7
// 191.282 us; speedup vs baseline: 1.3757x; 1.3757x over previous
//
#include <hip/hip_runtime.h>

#define B_   64
#define NQ_  1024
#define L_   128
#define E_   8192
#define M_   (B_*NQ_)
#define LDP  136        // padded LDS row stride (shorts)
#define TILE 2176       // 16*LDP u16 per tile

typedef unsigned short u16;
typedef unsigned int   u32;
typedef unsigned long long u64;
typedef __attribute__((ext_vector_type(8))) short short8;
typedef __attribute__((ext_vector_type(4))) float floatx4;

#define WVB() __builtin_amdgcn_wave_barrier()

__device__ __forceinline__ int imax2(int a, int b) { return a > b ? a : b; }
__device__ __forceinline__ int imin2(int a, int b) { return a < b ? a : b; }

__device__ __forceinline__ u16 f2bf(float f) {
    union { float f; u32 u; } v; v.f = f;
    return (u16)((v.u + 0x7fffu + ((v.u >> 16) & 1u)) >> 16);
}
__device__ __forceinline__ float bf2f(u16 u) {
    union { u32 u; float f; } v; v.u = ((u32)u) << 16;
    return v.f;
}
__device__ __forceinline__ float bf2f_lo(u32 jv) { return __uint_as_float(jv << 16); }
__device__ __forceinline__ float bf2f_hi(u32 jv) { return __uint_as_float(jv & 0xffff0000u); }
__device__ __forceinline__ floatx4 mfma16(short8 a, short8 b, floatx4 c) {
    return __builtin_amdgcn_mfma_f32_16x16x32_bf16(a, b, c, 0, 0, 0);
}
__device__ __forceinline__ short8 sfrag(const u16* t, int r0, int kb, int lane) {
    return *(const short8*)(t + (r0 + (lane & 15)) * LDP + kb * 32 + (lane >> 4) * 8);
}
// fragment-major weight fetch: coalesced 16B/lane from global (L2-hot)
__device__ __forceinline__ short8 wfrag(const u16* wf, int nt, int kb, int lane) {
    return *(const short8*)(wf + (((kb << 3) + nt) * 64 + lane) * 8);
}
__device__ __forceinline__ void frag_flush(const u16* t, u16* wf, int nt, int lane) {
#pragma unroll
    for (int kb = 0; kb < 4; ++kb)
        *(short8*)(wf + (((kb << 3) + nt) * 64 + lane) * 8) = sfrag(t, 0, kb, lane);
}
__device__ __forceinline__ short8 frag_cvt(const float* base, int r0, int ld, int kb, int lane) {
    const float* p = base + (size_t)(r0 + (lane & 15)) * ld + kb * 32 + (lane >> 4) * 8;
    short8 s;
#pragma unroll
    for (int j = 0; j < 8; ++j) s[j] = (short)f2bf(p[j]);
    return s;
}
__device__ __forceinline__ void tile_store(u16* t, const floatx4* acc, int lane) {
    int col = lane & 15, qd = lane >> 4;
#pragma unroll
    for (int nt = 0; nt < 8; ++nt)
#pragma unroll
        for (int r = 0; r < 4; ++r)
            t[(qd * 4 + r) * LDP + nt * 16 + col] = f2bf(acc[nt][r]);
}
__device__ __forceinline__ void tile_flush(const u16* t, u16* g, int lane) {
#pragma unroll
    for (int it = 0; it < 4; ++it) {
        int chunk = it * 64 + lane, row = chunk >> 4, c8 = chunk & 15;
        *(uint4*)(g + (size_t)row * 128 + c8 * 8) = *(const uint4*)(t + row * LDP + c8 * 8);
    }
}
// XCD-bijective swizzle for 1024 blocks: batch b only on XCD b&7.
__device__ __forceinline__ int blk_swz() {
    int r = blockIdx.x;
    int b = (((r >> 3) & 7) << 3) | (r & 7);
    return b * 16 + (r >> 6);
}

struct P {
    const int* ei; const float* attr; const float* z0;
    const float* e_w1; const float* e_b1; const float* e_w2; const float* e_b2;
    const float* n_w1; const float* n_b1; const float* ln_g; const float* ln_b;
    const float* n_w2; const float* n_b2;
    int* ofs; int2* ta; int* perm; float* degf;
    u16* wf;        // 6 fragment-major slots: 0=Wc0 1=Wd 2=We 3=Wf 4=Wc1 5=n2_1
    u16* w_n20;     // n2_0 row-major (fin GEMV)
    float* wl; float* vb2;
    float* rx; float* rci; float* rcj; float* rh; float* mx0;
    u16* c0t; u16* t1g; u16* ci1; u16* cj1;   // t1g fragment-major
    float* out;
};

// ---------------------------------------------------------------------------
// Setup, 20 blocks:
// 0 CSR + degree counting-sort perm; 1-2 n2_0 cvt; 3 n2_1->frag;
// 4-13 product GEMMs (B staged via LDS-transpose, coalesced);
// 14 rx; 15-17 rci/rcj/rh; 18 c0; 19 vb2+wl+zero mx0
// ---------------------------------------------------------------------------
__global__ __launch_bounds__(256) void k_setup(P p) {
    __shared__ __align__(16) char smem[35072];
    int tid = threadIdx.x, blk = blockIdx.x;
    int lane = tid & 63, w = tid >> 6, col = lane & 15, qd = lane >> 4;

    if (blk == 0) {                               // CSR build + degree sort
        int* cnt  = (int*)smem;                   // 1024
        int* wsum = cnt + 1024;                   // 4
        int* dh   = wsum + 4;                     // 64
        int* db   = dh + 64;                      // 64
        int* flag = db + 64;                      // 1
#pragma unroll
        for (int i = 0; i < 4; ++i) cnt[tid + i * 256] = 0;
        if (tid < 64) dh[tid] = 0;
        if (tid == 0) *flag = 1;
        __syncthreads();
        if (tid < 100 && p.ei[2 * tid + 1] != 0) atomicAnd(flag, 0);
        __syncthreads();
        int i64 = *flag;
        for (int e = tid; e < E_; e += 256) {
            int s = i64 ? p.ei[2 * e] : p.ei[e];
            atomicAdd(&cnt[s], 1);
        }
        __syncthreads();
        int q0 = tid * 4;
        int c0 = cnt[q0], c1 = cnt[q0 + 1], c2 = cnt[q0 + 2], c3 = cnt[q0 + 3];
        int tsum = c0 + c1 + c2 + c3, incl = tsum;
#pragma unroll
        for (int o = 1; o < 64; o <<= 1) {
            int t = __shfl_up(incl, o, 64);
            if (lane >= o) incl += t;
        }
        if (lane == 63) wsum[w] = incl;
        atomicAdd(&dh[imin2(c0, 63)], 1); atomicAdd(&dh[imin2(c1, 63)], 1);
        atomicAdd(&dh[imin2(c2, 63)], 1); atomicAdd(&dh[imin2(c3, 63)], 1);
        __syncthreads();
        int wo = 0;
        for (int i = 0; i < w; ++i) wo += wsum[i];
        int base = wo + incl - tsum;
        p.ofs[q0] = base; p.ofs[q0 + 1] = base + c0;
        p.ofs[q0 + 2] = base + c0 + c1; p.ofs[q0 + 3] = base + c0 + c1 + c2;
        p.degf[q0] = (float)c0; p.degf[q0 + 1] = (float)c1;
        p.degf[q0 + 2] = (float)c2; p.degf[q0 + 3] = (float)c3;
        if (tid == 0) p.ofs[NQ_] = E_;
        __syncthreads();
        cnt[q0] = base; cnt[q0 + 1] = base + c0;
        cnt[q0 + 2] = base + c0 + c1; cnt[q0 + 3] = base + c0 + c1 + c2;
        if (tid < 64) {                           // exclusive scan of 64 bins
            int v = dh[tid], inc = v;
#pragma unroll
            for (int o = 1; o < 64; o <<= 1) {
                int t = __shfl_up(inc, o, 64);
                if (tid >= o) inc += t;
            }
            db[tid] = inc - v;
        }
        __syncthreads();
        for (int e = tid; e < E_; e += 256) {
            int s = i64 ? p.ei[2 * e]        : p.ei[e];
            int t = i64 ? p.ei[2 * (E_ + e)] : p.ei[E_ + e];
            int pos = atomicAdd(&cnt[s], 1);
            p.ta[pos] = make_int2(t << 6, __float_as_int(p.attr[e]));
        }
        p.perm[atomicAdd(&db[imin2(c0, 63)], 1)] = q0;
        p.perm[atomicAdd(&db[imin2(c1, 63)], 1)] = q0 + 1;
        p.perm[atomicAdd(&db[imin2(c2, 63)], 1)] = q0 + 2;
        p.perm[atomicAdd(&db[imin2(c3, 63)], 1)] = q0 + 3;
        if (tid == 0) p.ta[E_] = make_int2(0, 0);   // pad slot
    } else if (blk <= 2) {                        // n2_0 row-major cvt, 2 halves
        int base = (blk - 1) * 8192;
        for (int idx = tid; idx < 8192; idx += 256)
            p.w_n20[base + idx] = f2bf(p.n_w2[base + idx]);
    } else if (blk == 3) {                        // n2_1 -> fragment-major slot 5
        const float* src = p.n_w2 + 16384;
        u16* dst = p.wf + 5 * 16384;
        for (int pr = w; pr < 32; pr += 4) {      // pr = kb*8+nt
            int kb = pr >> 3, nt = pr & 7;
            const float* s = src + (nt * 16 + col) * 128 + kb * 32 + qd * 8;
            short8 v;
#pragma unroll
            for (int j = 0; j < 8; ++j) v[j] = (short)f2bf(s[j]);
            *(short8*)(dst + (pr * 64 + lane) * 8) = v;
        }
    } else if (blk <= 13) {                       // product GEMMs, LDS-staged B
        int g = (blk - 4) >> 1, part = (blk - 4) & 1;
        const float* Pm; const float* Q; int ldp; u16* D;
        switch (g) {
            case 0:  Pm = p.n_w1 + 128;             ldp = 256; Q = p.e_w2;         D = p.wf;             break;
            case 1:  Pm = p.n_w1 + 32768 + 128;     ldp = 256; Q = p.e_w2 + 16384; D = p.wf + 4 * 16384; break;
            case 2:  Pm = p.e_w1 + 128 * 257;       ldp = 257; Q = p.n_w2;         D = p.wf + 1 * 16384; break;
            case 3:  Pm = p.e_w1 + 128 * 257 + 128; ldp = 257; Q = p.n_w2;         D = p.wf + 2 * 16384; break;
            default: Pm = p.n_w1 + 32768;           ldp = 256; Q = p.n_w2;         D = p.wf + 3 * 16384; break;
        }
        float* QT  = (float*)smem;                // [128][33] transposed panel
        u16* slots = (u16*)(smem + 16896);        // 4 x TILE
        int tile = part * 4 + w;                  // 0..7, one 16-row tile per wave
        int r0 = tile * 16;
        floatx4 acc[8] = {};
        for (int kb = 0; kb < 4; ++kb) {
            __syncthreads();
            // coalesced load of Q[kb*32..+32][0..128] -> QT[col][row]
#pragma unroll
            for (int i = 0; i < 4; ++i) {
                int off = (tid + i * 256) * 4;
                int r = off >> 7, c = off & 127;
                float4 v = *(const float4*)(Q + (size_t)(kb * 32 + r) * 128 + c);
                QT[(c + 0) * 33 + r] = v.x; QT[(c + 1) * 33 + r] = v.y;
                QT[(c + 2) * 33 + r] = v.z; QT[(c + 3) * 33 + r] = v.w;
            }
            __syncthreads();
            short8 a = frag_cvt(Pm, r0, ldp, kb, lane);
#pragma unroll
            for (int nt = 0; nt < 8; ++nt) {
                short8 bq;                        // B[k][n] = Q[k][n] from LDS
#pragma unroll
                for (int j = 0; j < 8; ++j)
                    bq[j] = (short)f2bf(QT[(nt * 16 + col) * 33 + qd * 8 + j]);
                acc[nt] = mfma16(a, bq, acc[nt]);
            }
        }
        __syncthreads();
        u16* slot = slots + w * TILE;
        tile_store(slot, acc, lane); WVB();
        frag_flush(slot, D, tile, lane);
    } else if (blk == 14) {                       // rx = z0@n1a0^T + n_b1_0
        int r0 = w * 16;
        floatx4 acc[8] = {};
#pragma unroll
        for (int kb = 0; kb < 4; ++kb) {
            short8 a = frag_cvt(p.z0, r0, 128, kb, lane);
#pragma unroll
            for (int nt = 0; nt < 8; ++nt)
                acc[nt] = mfma16(a, frag_cvt(p.n_w1, nt * 16, 256, kb, lane), acc[nt]);
        }
#pragma unroll
        for (int nt = 0; nt < 8; ++nt) {
            int cg = nt * 16 + col; float bv = p.n_b1[cg];
#pragma unroll
            for (int r = 0; r < 4; ++r) p.rx[(r0 + qd * 4 + r) * 128 + cg] = acc[nt][r] + bv;
        }
    } else if (blk <= 17) {                       // rci/rcj/rh = (z0+n_b2_0)@W^T (+bias)
        int r0 = w * 16;
        const float* Wp; int ld; const float* bias; float* dst;
        if (blk == 15)      { Wp = p.e_w1 + 128 * 257;       ld = 257; bias = p.e_b1 + 128; dst = p.rci; }
        else if (blk == 16) { Wp = p.e_w1 + 128 * 257 + 128; ld = 257; bias = nullptr;      dst = p.rcj; }
        else                { Wp = p.n_w1 + 32768;           ld = 256; bias = p.n_b1 + 128; dst = p.rh;  }
        floatx4 acc[8] = {};
#pragma unroll
        for (int kb = 0; kb < 4; ++kb) {
            short8 a;
            int rr = (r0 + col) * 128, kk = kb * 32 + qd * 8;
#pragma unroll
            for (int j = 0; j < 8; ++j) a[j] = (short)f2bf(p.z0[rr + kk + j] + p.n_b2[kk + j]);
#pragma unroll
            for (int nt = 0; nt < 8; ++nt)
                acc[nt] = mfma16(a, frag_cvt(Wp, nt * 16, ld, kb, lane), acc[nt]);
        }
#pragma unroll
        for (int nt = 0; nt < 8; ++nt) {
            int cg = nt * 16 + col;
            float bv = bias ? bias[cg] : 0.0f;
#pragma unroll
            for (int r = 0; r < 4; ++r) dst[(r0 + qd * 4 + r) * 128 + cg] = acc[nt][r] + bv;
        }
    } else if (blk == 18) {                       // c0 = z0@(W1a0+W1b0)^T + e_b1_0
        int r0 = w * 16;
        floatx4 a1[8] = {};
#pragma unroll
        for (int kb = 0; kb < 4; ++kb) {
            short8 a = frag_cvt(p.z0, r0, 128, kb, lane);
#pragma unroll
            for (int nt = 0; nt < 8; ++nt) {
                a1[nt] = mfma16(a, frag_cvt(p.e_w1,       nt * 16, 257, kb, lane), a1[nt]);
                a1[nt] = mfma16(a, frag_cvt(p.e_w1 + 128, nt * 16, 257, kb, lane), a1[nt]);
            }
        }
#pragma unroll
        for (int nt = 0; nt < 8; ++nt) {
            float bv = p.e_b1[nt * 16 + col];
#pragma unroll
            for (int r = 0; r < 4; ++r) a1[nt][r] += bv;
        }
        u16* slot = (u16*)smem + w * TILE;
        tile_store(slot, a1, lane); WVB();
        tile_flush(slot, p.c0t + (size_t)r0 * 128, lane);
    } else {                                      // vb2 (vectorized) + wl + zero mx0
        int k = tid >> 7, c = tid & 127;
        const float4* wp = (const float4*)(p.n_w1 + k * 32768 + c * 256 + 128);
        const float4* bp = (const float4*)(p.e_b2 + k * 128);
        float s0 = 0.f, s1 = 0.f, s2 = 0.f, s3 = 0.f;
#pragma unroll
        for (int n4 = 0; n4 < 32; ++n4) {
            float4 a = wp[n4], bv = bp[n4];
            s0 += a.x * bv.x; s1 += a.y * bv.y; s2 += a.z * bv.z; s3 += a.w * bv.w;
        }
        p.vb2[tid] = (s0 + s1) + (s2 + s3);
        p.wl[tid]  = p.e_w1[k * 128 * 257 + c * 257 + 256];
        for (int i = tid; i < 8192; i += 256) p.mx0[i] = 0.0f;
    }
}

// ---------------------------------------------------------------------------
// node0, 1024 blocks x 4 waves x 16 rows (sorted rows, lean/tail edge phase):
// fused round-0 edge (no gather) -> x0 GEMM -> LN -> mx0 atomics;
// ci1 physical rows; cj1 scattered to ORIGINAL q; t1 fragment-major.
// ---------------------------------------------------------------------------
__global__ __launch_bounds__(256, 4) void k_node0(P p) {
    __shared__ __align__(16) char smem[35072];
    u16* xt = (u16*)smem;                  // 4 waves x 1 tile
    u16* ob = (u16*)(smem + 17408);        // 4 waves x 1 tile staging
    int* qmap = (int*)(smem + 34816);      // 4 waves x 16 ints
    int tid = threadIdx.x, lane = tid & 63, w = tid >> 6;
    int col = lane & 15, qd = lane >> 4;
    int blk = blk_swz();
    int rowbase = blk * 64 + w * 16;
    int b = blk >> 4;
    {   // qmap: wave W handles sorted groups (W, 127-W)
        int W = (blk & 15) * 4 + w;
        if (lane < 16)
            qmap[w * 16 + lane] = p.perm[lane < 8 ? W * 8 + lane : (127 - W) * 8 + lane - 8];
        WVB();
    }

    // ---- fused round-0 edge aggregation (sorted, lean/tail, 8-row groups) ----
    {
        u32 cv = ((const u32*)p.c0t)[b * 64 + lane];
        float cx = bf2f((u16)(cv & 0xffffu)), cy = bf2f((u16)(cv >> 16));
        float2 wl2 = ((const float2*)p.wl)[lane];
        const int* tay = (const int*)p.ta;        // .y at 2*idx+1
        for (int g2 = 0; g2 < 2; ++g2) {
            int st[8], en[8];
            float ax[8] = {}, ay[8] = {};
#pragma unroll
            for (int j = 0; j < 8; ++j) {
                int q = qmap[w * 16 + g2 * 8 + j];
                st[j] = p.ofs[q]; en[j] = p.ofs[q + 1];
            }
            int mn = en[0] - st[0], mx = mn;
#pragma unroll
            for (int j = 1; j < 8; ++j) {
                mn = imin2(mn, en[j] - st[j]); mx = imax2(mx, en[j] - st[j]);
            }
            float ac[8];
#pragma unroll
            for (int j = 0; j < 8; ++j) {         // clamped init prefetch
                int last = en[j] - 1;
                int safe = st[j] < en[j] ? st[j] : (last >= 0 ? last : 0);
                ac[j] = __int_as_float(tay[2 * safe + 1]);
            }
            for (int k2 = 0; k2 < mn; ++k2) {     // lean: no masks, no clamps
                float an[8];
#pragma unroll
                for (int j = 0; j < 8; ++j) an[j] = __int_as_float(tay[2 * (st[j] + k2 + 1) + 1]);
#pragma unroll
                for (int j = 0; j < 8; ++j) {
                    ax[j] += fmaxf(cx + ac[j] * wl2.x, 0.f);
                    ay[j] += fmaxf(cy + ac[j] * wl2.y, 0.f);
                    ac[j] = an[j];
                }
            }
            for (int k2 = mn; k2 < mx; ++k2) {    // masked tail
                float an[8];
#pragma unroll
                for (int j = 0; j < 8; ++j) {
                    int idx = st[j] + k2 + 1, last = en[j] - 1;
                    int safe = idx < en[j] ? idx : (last >= 0 ? last : 0);
                    an[j] = __int_as_float(tay[2 * safe + 1]);
                }
#pragma unroll
                for (int j = 0; j < 8; ++j) {
                    bool v = st[j] + k2 < en[j];
                    ax[j] += v ? fmaxf(cx + ac[j] * wl2.x, 0.f) : 0.f;
                    ay[j] += v ? fmaxf(cy + ac[j] * wl2.y, 0.f) : 0.f;
                    ac[j] = an[j];
                }
            }
#pragma unroll
            for (int j = 0; j < 8; ++j) {
                int r = g2 * 8 + j;
                u32* tp = (u32*)(xt + (size_t)w * TILE + r * LDP);
                tp[lane] = (u32)f2bf(ax[j]) | ((u32)f2bf(ay[j]) << 16);
            }
        }
    }
    WVB();

    floatx4 xa[8] = {};
#pragma unroll
    for (int kb = 0; kb < 4; ++kb) {
        short8 a = sfrag(xt + w * TILE, 0, kb, lane);
#pragma unroll
        for (int nt = 0; nt < 8; ++nt) xa[nt] = mfma16(a, wfrag(p.wf, nt, kb, lane), xa[nt]);
    }
    WVB();
    float s8[8] = {};
#pragma unroll
    for (int nt = 0; nt < 8; ++nt) {
        int cg = nt * 16 + col;
        float base = p.rx[b * 128 + cg], vb = p.vb2[cg];
#pragma unroll
        for (int r = 0; r < 4; ++r) {
            int q = qmap[w * 16 + qd * 4 + r];
            xa[nt][r] = fmaxf(xa[nt][r] + base + p.degf[q] * vb, 0.f);
        }
    }
#pragma unroll
    for (int r = 0; r < 4; ++r) {
        float s = 0.f, s2 = 0.f;
#pragma unroll
        for (int nt = 0; nt < 8; ++nt) { float v = xa[nt][r]; s += v; s2 += v * v; }
#pragma unroll
        for (int o = 1; o < 16; o <<= 1) { s += __shfl_xor(s, o, 64); s2 += __shfl_xor(s2, o, 64); }
        float mu = s * (1.f / 128.f), var = s2 * (1.f / 128.f) - mu * mu;
        float rs = rsqrtf(var + 1e-5f);
#pragma unroll
        for (int nt = 0; nt < 8; ++nt) {
            int cg = nt * 16 + col;
            float xv = (xa[nt][r] - mu) * rs * p.ln_g[cg] + p.ln_b[cg];
            xa[nt][r] = xv;
            s8[nt] += xv;
        }
    }
    tile_store(xt + w * TILE, xa, lane);
#pragma unroll
    for (int nt = 0; nt < 8; ++nt) {
        s8[nt] += __shfl_xor(s8[nt], 16, 64);
        s8[nt] += __shfl_xor(s8[nt], 32, 64);
    }
    if (lane < 16) {
#pragma unroll
        for (int nt = 0; nt < 8; ++nt)
            atomicAdd(p.mx0 + b * 128 + nt * 16 + lane, s8[nt]);
    }
    WVB();
#pragma unroll
    for (int ph = 0; ph < 3; ++ph) {
        const u16* wfp = p.wf + ((ph == 0) ? 1 : (ph == 1) ? 2 : 3) * 16384;
        const float* rt = (ph == 0) ? p.rci : (ph == 1) ? p.rcj : p.rh;
        floatx4 ca[8] = {};
#pragma unroll
        for (int kb = 0; kb < 4; ++kb) {
            short8 a = sfrag(xt + w * TILE, 0, kb, lane);
#pragma unroll
            for (int nt = 0; nt < 8; ++nt) ca[nt] = mfma16(a, wfrag(wfp, nt, kb, lane), ca[nt]);
        }
#pragma unroll
        for (int nt = 0; nt < 8; ++nt) {
            float rc = rt[b * 128 + nt * 16 + col];
#pragma unroll
            for (int r = 0; r < 4; ++r) ca[nt][r] += rc;
        }
        if (ph == 2) {                            // t1 -> fragment-major, 8B/lane
            u64* t1f = (u64*)p.t1g;
            int tile = blk * 4 + w;               // physical tile index
#pragma unroll
            for (int nt = 0; nt < 8; ++nt) {
                u32 lo = (u32)f2bf(ca[nt][0]) | ((u32)f2bf(ca[nt][1]) << 16);
                u32 hi = (u32)f2bf(ca[nt][2]) | ((u32)f2bf(ca[nt][3]) << 16);
                t1f[(size_t)(tile * 8 + nt) * 64 + lane] = (u64)lo | ((u64)hi << 32);
            }
        } else if (ph == 0) {                     // ci1: physical rows, contiguous
            tile_store(ob + w * TILE, ca, lane);
            WVB();
            tile_flush(ob + w * TILE, p.ci1 + (size_t)rowbase * 128, lane);
            WVB();
        } else {                                  // cj1: scatter to ORIGINAL q
            tile_store(ob + w * TILE, ca, lane);
            WVB();
#pragma unroll
            for (int it = 0; it < 4; ++it) {
                int chunk = it * 64 + lane, row = chunk >> 4, c8 = chunk & 15;
                int q = qmap[w * 16 + row];
                *(uint4*)(p.cj1 + ((size_t)b * NQ_ + q) * 128 + c8 * 8) =
                    *(const uint4*)(ob + w * TILE + row * LDP + c8 * 8);
            }
            WVB();
        }
    }
}

// ---------------------------------------------------------------------------
// node1, 1024 blocks x 4 waves x 16 rows (sorted): fused round-1 gather
// (lean/tail, 8 in flight) -> x1 GEMM; t1 fragment-major; LN;
// out += mean(x1@n2_1); fin GEMV. XCD-swizzled (cj1[b] L2-resident).
// ---------------------------------------------------------------------------
__global__ __launch_bounds__(256, 4) void k_node1(P p) {
    __shared__ __align__(16) char smem[35072];
    u16* xt = (u16*)smem;
    u16* ob = (u16*)(smem + 17408);
    int* qmap = (int*)(smem + 34816);
    int tid = threadIdx.x, lane = tid & 63, w = tid >> 6;
    int col = lane & 15, qd = lane >> 4;
    int blk = blk_swz();
    int b = blk >> 4;
    {   // qmap: wave W handles sorted groups (W, 127-W)
        int W = (blk & 15) * 4 + w;
        if (lane < 16)
            qmap[w * 16 + lane] = p.perm[lane < 8 ? W * 8 + lane : (127 - W) * 8 + lane - 8];
        WVB();
    }

    // ---- fused round-1 edge aggregation (sorted, lean/tail) ----
    {
        float2 wl2 = ((const float2*)(p.wl + 128))[lane];
        const u32* cip = (const u32*)p.ci1;
        const u32* cjp = (const u32*)p.cj1 + (size_t)b * NQ_ * 64;
        int rowbase = blk * 64 + w * 16;
        for (int g2 = 0; g2 < 2; ++g2) {
            int st[8], en[8];
            float ax[8] = {}, ay[8] = {}, cx[8], cy[8];
#pragma unroll
            for (int j = 0; j < 8; ++j) {
                int prow = rowbase + g2 * 8 + j;
                u32 cv = cip[(size_t)prow * 64 + lane];
                cx[j] = bf2f((u16)(cv & 0xffffu)); cy[j] = bf2f((u16)(cv >> 16));
                int q = qmap[w * 16 + g2 * 8 + j];
                st[j] = p.ofs[q]; en[j] = p.ofs[q + 1];
            }
            int mn = en[0] - st[0], mx = mn;
#pragma unroll
            for (int j = 1; j < 8; ++j) {
                mn = imin2(mn, en[j] - st[j]); mx = imax2(mx, en[j] - st[j]);
            }
            int tc[8]; float ac[8];
#pragma unroll
            for (int j = 0; j < 8; ++j) {         // clamped init prefetch
                int last = en[j] - 1;
                int safe = st[j] < en[j] ? st[j] : (last >= 0 ? last : 0);
                int2 tv = p.ta[safe];
                tc[j] = tv.x; ac[j] = __int_as_float(tv.y);
            }
            for (int k2 = 0; k2 < mn; ++k2) {     // lean path
                u32 jv[8];
#pragma unroll
                for (int j = 0; j < 8; ++j) jv[j] = cjp[(u32)(tc[j] + lane)];
                int2 tv[8];
#pragma unroll
                for (int j = 0; j < 8; ++j) tv[j] = p.ta[st[j] + k2 + 1];
#pragma unroll
                for (int j = 0; j < 8; ++j) {
                    ax[j] += fmaxf(cx[j] + bf2f_lo(jv[j]) + ac[j] * wl2.x, 0.f);
                    ay[j] += fmaxf(cy[j] + bf2f_hi(jv[j]) + ac[j] * wl2.y, 0.f);
                    tc[j] = tv[j].x; ac[j] = __int_as_float(tv[j].y);
                }
            }
            for (int k2 = mn; k2 < mx; ++k2) {    // masked tail
                u32 jv[8];
#pragma unroll
                for (int j = 0; j < 8; ++j) jv[j] = cjp[(u32)(tc[j] + lane)];
                int2 tv[8];
#pragma unroll
                for (int j = 0; j < 8; ++j) {
                    int idx = st[j] + k2 + 1, last = en[j] - 1;
                    int safe = idx < en[j] ? idx : (last >= 0 ? last : 0);
                    tv[j] = p.ta[safe];
                }
#pragma unroll
                for (int j = 0; j < 8; ++j) {
                    bool v = st[j] + k2 < en[j];
                    float vx = fmaxf(cx[j] + bf2f_lo(jv[j]) + ac[j] * wl2.x, 0.f);
                    float vy = fmaxf(cy[j] + bf2f_hi(jv[j]) + ac[j] * wl2.y, 0.f);
                    ax[j] += v ? vx : 0.f;
                    ay[j] += v ? vy : 0.f;
                    tc[j] = tv[j].x; ac[j] = __int_as_float(tv[j].y);
                }
            }
#pragma unroll
            for (int j = 0; j < 8; ++j) {
                int r = g2 * 8 + j;
                u32* tp = (u32*)(xt + (size_t)w * TILE + r * LDP);
                tp[lane] = (u32)f2bf(ax[j]) | ((u32)f2bf(ay[j]) << 16);
            }
        }
    }
    WVB();

    const u16* wc1 = p.wf + 4 * 16384;
    floatx4 x1[8] = {};
#pragma unroll
    for (int kb = 0; kb < 4; ++kb) {
        short8 a = sfrag(xt + w * TILE, 0, kb, lane);
#pragma unroll
        for (int nt = 0; nt < 8; ++nt) x1[nt] = mfma16(a, wfrag(wc1, nt, kb, lane), x1[nt]);
    }
    const float* vb21 = p.vb2 + 128;
    const u64* t1f = (const u64*)p.t1g;
    int tile = blk * 4 + w;                       // physical tile index
#pragma unroll
    for (int nt = 0; nt < 8; ++nt) {
        int cg = nt * 16 + col;
        float vb = vb21[cg];
        u64 tv = t1f[(size_t)(tile * 8 + nt) * 64 + lane];   // coalesced 8B/lane
        float tvf[4] = { bf2f((u16)tv),         bf2f((u16)(tv >> 16)),
                         bf2f((u16)(tv >> 32)), bf2f((u16)(tv >> 48)) };
#pragma unroll
        for (int r = 0; r < 4; ++r) {
            int q = qmap[w * 16 + qd * 4 + r];
            x1[nt][r] = fmaxf(x1[nt][r] + tvf[r] + p.degf[q] * vb, 0.f);
        }
    }
#pragma unroll
    for (int r = 0; r < 4; ++r) {
        float s = 0.f, s2 = 0.f;
#pragma unroll
        for (int nt = 0; nt < 8; ++nt) { float v = x1[nt][r]; s += v; s2 += v * v; }
#pragma unroll
        for (int o = 1; o < 16; o <<= 1) { s += __shfl_xor(s, o, 64); s2 += __shfl_xor(s2, o, 64); }
        float mu = s * (1.f / 128.f), var = s2 * (1.f / 128.f) - mu * mu;
        float rs = rsqrtf(var + 1e-5f);
#pragma unroll
        for (int nt = 0; nt < 8; ++nt) {
            int cg = nt * 16 + col;
            x1[nt][r] = (x1[nt][r] - mu) * rs * p.ln_g[128 + cg] + p.ln_b[128 + cg];
        }
    }
    // mean(x1@n2_1): per-wave staging through ob slot
    const u16* n21 = p.wf + 5 * 16384;
    float s9[8] = {};
    tile_store(ob + w * TILE, x1, lane);
    WVB();
    {
        floatx4 ma[8] = {};
#pragma unroll
        for (int kb = 0; kb < 4; ++kb) {
            short8 a = sfrag(ob + w * TILE, 0, kb, lane);
#pragma unroll
            for (int nt = 0; nt < 8; ++nt) ma[nt] = mfma16(a, wfrag(n21, nt, kb, lane), ma[nt]);
        }
#pragma unroll
        for (int nt = 0; nt < 8; ++nt)
#pragma unroll
            for (int r = 0; r < 4; ++r) s9[nt] += ma[nt][r];
    }
#pragma unroll
    for (int nt = 0; nt < 8; ++nt) {
        s9[nt] += __shfl_xor(s9[nt], 16, 64);
        s9[nt] += __shfl_xor(s9[nt], 32, 64);
    }
    if (lane < 16) {
#pragma unroll
        for (int nt = 0; nt < 8; ++nt)
            atomicAdd(p.out + b * 128 + nt * 16 + lane, s9[nt] * (1.f / 1024.f));
    }
    // fin: out[b] += z0[b] + n_b2_0 + n_b2_1 + mx0[b]@n2_0^T / 1024  (vectorized)
    if ((blk & 15) == 0 && tid < 128) {
        int c = tid;
        const float* mx = p.mx0 + b * 128;
        float s = 0.f;
#pragma unroll
        for (int k8 = 0; k8 < 16; ++k8) {
            short8 wv = *(const short8*)(p.w_n20 + c * 128 + k8 * 8);
            const float* mxp = mx + k8 * 8;
#pragma unroll
            for (int j = 0; j < 8; ++j) s += mxp[j] * bf2f((u16)wv[j]);
        }
        float acc = p.z0[b * 128 + c] + p.n_b2[c] + p.n_b2[128 + c] + s * (1.f / 1024.f);
        atomicAdd(p.out + b * 128 + c, acc);
    }
}

// ---------------------------------------------------------------------------
extern "C" void kernel_launch(void* const* d_in, const int* in_sizes, int n_in,
                              void* d_out, int out_size, void* d_ws, size_t ws_size,
                              hipStream_t stream) {
    P p;
    p.z0   = (const float*)d_in[0];
    p.ei   = (const int*)d_in[1];
    p.attr = (const float*)d_in[2];
    p.e_w1 = (const float*)d_in[4];
    p.e_b1 = (const float*)d_in[5];
    p.e_w2 = (const float*)d_in[6];
    p.e_b2 = (const float*)d_in[7];
    p.n_w1 = (const float*)d_in[8];
    p.n_b1 = (const float*)d_in[9];
    p.ln_g = (const float*)d_in[10];
    p.ln_b = (const float*)d_in[11];
    p.n_w2 = (const float*)d_in[12];
    p.n_b2 = (const float*)d_in[13];
    p.out  = (float*)d_out;

    const size_t H = (size_t)M_ * L_;
    float* f  = (float*)d_ws;
    p.degf = f;                           // 1024
    p.wl   = f + 1024;                    // 256
    p.vb2  = p.wl + 256;                  // 256
    p.rx   = p.vb2 + 256;                 // 8192
    p.rci  = p.rx + 8192;                 // 8192
    p.rcj  = p.rci + 8192;                // 8192
    p.rh   = p.rcj + 8192;                // 8192
    p.mx0  = p.rh + 8192;                 // 8192
    p.ofs  = (int*)(p.mx0 + 8192);        // 1056
    p.perm = p.ofs + 1056;                // 1024
    p.ta   = (int2*)(p.perm + 1024);      // E_+8 int2
    p.wf    = (u16*)(p.ta + E_ + 8);      // 6*16384
    p.w_n20 = p.wf + 6 * 16384;           // 16384
    p.c0t   = p.w_n20 + 16384;            // 8192
    p.t1g   = p.c0t + 8192;               // H (fragment-major)
    p.ci1   = p.t1g + H;                  // H
    p.cj1   = p.ci1 + H;                  // H

    hipMemsetAsync(p.out, 0, 8192 * sizeof(float), stream);

    k_setup<<<20, 256, 0, stream>>>(p);
    k_node0<<<1024, 256, 0, stream>>>(p);
    k_node1<<<1024, 256, 0, stream>>>(p);
}